// Round 13
// baseline (36.495 us; speedup 1.0000x reference)
//
#include <hip/hip_runtime.h>

#define BB 16
#define QQ 200
#define NN 200
#define CC 64
#define TT 100
#define GG 50
#define SS 4
#define EE (GG*SS)   // 200
#define QPB 2        // q's per block
#define PAD 112      // padded distinct-row slots (7 iters x 16 groups); cnt<=100

// Fused kernel, QPB=2 + deduped row stats with compile-time padded loop.
//  - per block: sort (stable argsort), mark distinct referenced rows,
//    serial ascending scan -> n_list[slot], repack edges to slot*64+class
//  - stats: 7 fully-unrolled iterations over PAD slots, predicate t<cnt is
//    GROUP-uniform (whole 16-lane group on/off -> shfl tree stays clean)
//  - gather for both q's, group-of-4 sum, broadcast write.
__global__ __launch_bounds__(256) void edge_cost_fused_kernel(
    const float* __restrict__ edges,          // [B,Q,N,C]
    const int* __restrict__ query_indices,    // [B,T]
    const int* __restrict__ target_indices,   // [B,T]
    const int* __restrict__ col_ids,          // [B,E]
    const int* __restrict__ edge_tgt,         // [B,E]
    float* __restrict__ out)                  // [B,Q,B*G]
{
    const int blk = blockIdx.x;
    const int b  = blk / (QQ / QPB);
    const int q0 = (blk % (QQ / QPB)) * QPB;
    const int tid = threadIdx.x;

    __shared__ int   tk[TT];
    __shared__ int   qi[TT];
    __shared__ int   sq_sh[TT];
    __shared__ int   ep_sh[EE];          // t*64+c, repacked to slot*64+c
    __shared__ int   used[NN];
    __shared__ int   slotmap[NN];
    __shared__ int   n_list[PAD];
    __shared__ int   cnt_sh;
    __shared__ float sm_sh[QPB][PAD];
    __shared__ float cost_sh[QPB][GG];

    if (tid < TT) {
        tk[tid] = target_indices[b * TT + tid];
        qi[tid] = query_indices[b * TT + tid];
    }
    if (tid < EE) {
        const int t_e = col_ids[b * EE + tid];
        const int c_e = edge_tgt[b * EE + tid];
        ep_sh[tid] = t_e * 64 + c_e;
    }
    if (tid < NN) used[tid] = 0;
    __syncthreads();

    // Stable argsort by rank (ties broken by original index).
    if (tid < TT) {
        const int key = tk[tid];
        int rank = 0;
        #pragma unroll 4
        for (int j = 0; j < TT; ++j) {
            const int kj = tk[j];
            rank += (kj < key) || (kj == key && j < tid);
        }
        sq_sh[rank] = qi[tid];
    }
    __syncthreads();

    // Mark distinct referenced rows.
    if (tid < EE) used[sq_sh[ep_sh[tid] >> 6]] = 1;   // benign race, all write 1
    __syncthreads();

    // Serial ascending scan -> slot map + n_list (hidden by other blocks).
    if (tid == 0) {
        int c = 0;
        for (int n = 0; n < NN; ++n)
            if (used[n]) { slotmap[n] = c; n_list[c] = n; ++c; }
        cnt_sh = c;
        for (int s = c; s < PAD; ++s) n_list[s] = 0;  // safe pad
    }
    __syncthreads();

    // Repack edges: slot*64 + class (own-slot read/write, no race).
    if (tid < EE) {
        const int pack = ep_sh[tid];
        ep_sh[tid] = slotmap[sq_sh[pack >> 6]] * 64 + (pack & 63);
    }

    const int cnt = cnt_sh;
    const float* base = edges + ((size_t)(b * QQ + q0)) * NN * CC;

    // Stats: sum-exp per distinct row, both slabs; 7 unrolled predicated
    // iterations (group-uniform predicate).
    const int grp  = tid >> 4;
    const int lane = tid & 15;
    #pragma unroll
    for (int it = 0; it < PAD / 16; ++it) {
        const int t = grp + it * 16;
        if (t < cnt) {
            const float* r0 = base + (size_t)n_list[t] * CC;
            const float4 v0 = reinterpret_cast<const float4*>(r0)[lane];
            const float4 v1 = reinterpret_cast<const float4*>(r0 + NN * CC)[lane];
            float e0 = __expf(v0.x) + __expf(v0.y) + __expf(v0.z) + __expf(v0.w);
            float e1 = __expf(v1.x) + __expf(v1.y) + __expf(v1.z) + __expf(v1.w);
            #pragma unroll
            for (int off = 1; off < 16; off <<= 1) {
                e0 += __shfl_xor(e0, off, 64);
                e1 += __shfl_xor(e1, off, 64);
            }
            if (lane == 0) { sm_sh[0][t] = e0; sm_sh[1][t] = e1; }
        }
    }
    __syncthreads();

    // Gather: per-edge probability for both q's, group-of-4 reduce.
    if (tid < EE) {
        const int pack = ep_sh[tid];
        const int slot = pack >> 6;
        const int c    = pack & 63;
        const size_t roff = (size_t)n_list[slot] * CC + c;
        const float x0 = base[roff];
        const float x1 = base[(size_t)NN * CC + roff];
        float p0 = __expf(x0) / sm_sh[0][slot];
        float p1 = __expf(x1) / sm_sh[1][slot];
        p0 += __shfl_xor(p0, 1, 64);  p1 += __shfl_xor(p1, 1, 64);
        p0 += __shfl_xor(p0, 2, 64);  p1 += __shfl_xor(p1, 2, 64);
        if ((tid & 3) == 0) {
            cost_sh[0][tid >> 2] = -p0;
            cost_sh[1][tid >> 2] = -p1;
        }
    }
    __syncthreads();

    // Broadcast write: out[b2, q0+qq, b*G+g] for all b2, both q's.
    for (int i = tid; i < QPB * BB * GG; i += 256) {
        const int qq = i / (BB * GG);
        const int r  = i % (BB * GG);
        const int b2 = r / GG;
        const int g  = r % GG;
        out[((size_t)b2 * QQ + q0 + qq) * (BB * GG) + b * GG + g] = cost_sh[qq][g];
    }
}

extern "C" void kernel_launch(void* const* d_in, const int* in_sizes, int n_in,
                              void* d_out, int out_size, void* d_ws, size_t ws_size,
                              hipStream_t stream) {
    const float* edges = (const float*)d_in[0];          // [B,Q,N,C] f32
    const int* query_indices  = (const int*)d_in[1];     // [B,T]
    const int* target_indices = (const int*)d_in[2];     // [B,T]
    const int* col_ids        = (const int*)d_in[3];     // [B,G,S]
    const int* edge_tgt       = (const int*)d_in[4];     // [B,G,S]
    float* out = (float*)d_out;                          // [B,Q,B*G]

    edge_cost_fused_kernel<<<BB * (QQ / QPB), 256, 0, stream>>>(
        edges, query_indices, target_indices, col_ids, edge_tgt, out);
}

// Round 14
// 25.972 us; speedup vs baseline: 1.4052x; 1.4052x over previous
//
#include <hip/hip_runtime.h>

#define BB 16
#define QQ 200
#define NN 200
#define CC 64
#define TT 100
#define GG 50
#define SS 4
#define EE (GG*SS)   // 200
#define QPB 2        // q's per block; all loop bounds compile-time

// Fused kernel, QPB=2, sort OFF the critical path:
//  - stats: sum-exp per ORIGINAL t (row qi[t], read direct from global —
//    L2 broadcast), issues immediately at kernel entry, no barrier before.
//  - sort: rank-invert into order_sh[rank]=tid, overlapped with in-flight
//    stats loads; used only by the gather phase.
//  - gather: o=order[t_e]; row qi[o]; denom sm[qq][o]; group-of-4 sum.
//  - broadcast write.
__global__ __launch_bounds__(256) void edge_cost_fused_kernel(
    const float* __restrict__ edges,          // [B,Q,N,C]
    const int* __restrict__ query_indices,    // [B,T]
    const int* __restrict__ target_indices,   // [B,T]
    const int* __restrict__ col_ids,          // [B,E]
    const int* __restrict__ edge_tgt,         // [B,E]
    float* __restrict__ out)                  // [B,Q,B*G]
{
    const int blk = blockIdx.x;
    const int b  = blk / (QQ / QPB);
    const int q0 = (blk % (QQ / QPB)) * QPB;
    const int tid = threadIdx.x;

    __shared__ int   tk[TT];
    __shared__ int   qi[TT];
    __shared__ int   order_sh[TT];       // sorted pos -> original index
    __shared__ int   ep_sh[EE];          // t*64 + class packed
    __shared__ float sm_sh[QPB][TT];     // sum-exp indexed by ORIGINAL t
    __shared__ float cost_sh[QPB][GG];

    // Stage for sort/gather phases (no barrier needed before stats).
    if (tid < TT) {
        tk[tid] = target_indices[b * TT + tid];
        qi[tid] = query_indices[b * TT + tid];
    }
    if (tid < EE) {
        const int t_e = col_ids[b * EE + tid];
        const int c_e = edge_tgt[b * EE + tid];
        ep_sh[tid] = t_e * 64 + c_e;
    }

    const float* base = edges + ((size_t)(b * QQ + q0)) * NN * CC;
    const int* qi_g = query_indices + b * TT;

    // Stats: sum-exp per original t, both slabs; 16 groups x 16 lanes.
    // Row index read DIRECT from global (same addr across group -> L1/L2
    // broadcast). Compile-time trip bound -> full unroll, loads pipelined.
    const int grp  = tid >> 4;
    const int lane = tid & 15;
    #pragma unroll
    for (int it = 0; it < 7; ++it) {
        const int t = grp + it * 16;
        if (t < TT) {                              // static: only it=6 predicated
            const int n = qi_g[t];
            const float* r0 = base + (size_t)n * CC;
            const float4 v0 = reinterpret_cast<const float4*>(r0)[lane];
            const float4 v1 = reinterpret_cast<const float4*>(r0 + NN * CC)[lane];
            float e0 = __expf(v0.x) + __expf(v0.y) + __expf(v0.z) + __expf(v0.w);
            float e1 = __expf(v1.x) + __expf(v1.y) + __expf(v1.z) + __expf(v1.w);
            #pragma unroll
            for (int off = 1; off < 16; off <<= 1) {
                e0 += __shfl_xor(e0, off, 64);
                e1 += __shfl_xor(e1, off, 64);
            }
            if (lane == 0) { sm_sh[0][t] = e0; sm_sh[1][t] = e1; }
        }
    }
    __syncthreads();   // covers tk/qi/ep staging AND sm_sh writes

    // Stable argsort rank inversion: order_sh[rank] = original index.
    if (tid < TT) {
        const int key = tk[tid];
        int rank = 0;
        #pragma unroll 4
        for (int j = 0; j < TT; ++j) {
            const int kj = tk[j];
            rank += (kj < key) || (kj == key && j < tid);
        }
        order_sh[rank] = tid;
    }
    __syncthreads();

    // Gather: per-edge probability for both q's, group-of-4 reduce.
    if (tid < EE) {
        const int pack = ep_sh[tid];
        const int t_e = pack >> 6;
        const int c   = pack & 63;
        const int o   = order_sh[t_e];           // original index
        const size_t roff = (size_t)qi[o] * CC + c;
        const float x0 = base[roff];
        const float x1 = base[(size_t)NN * CC + roff];
        float p0 = __expf(x0) / sm_sh[0][o];
        float p1 = __expf(x1) / sm_sh[1][o];
        p0 += __shfl_xor(p0, 1, 64);  p1 += __shfl_xor(p1, 1, 64);
        p0 += __shfl_xor(p0, 2, 64);  p1 += __shfl_xor(p1, 2, 64);
        if ((tid & 3) == 0) {
            cost_sh[0][tid >> 2] = -p0;
            cost_sh[1][tid >> 2] = -p1;
        }
    }
    __syncthreads();

    // Broadcast write: out[b2, q0+qq, b*G+g] for all b2, both q's.
    for (int i = tid; i < QPB * BB * GG; i += 256) {
        const int qq = i / (BB * GG);
        const int r  = i % (BB * GG);
        const int b2 = r / GG;
        const int g  = r % GG;
        out[((size_t)b2 * QQ + q0 + qq) * (BB * GG) + b * GG + g] = cost_sh[qq][g];
    }
}

extern "C" void kernel_launch(void* const* d_in, const int* in_sizes, int n_in,
                              void* d_out, int out_size, void* d_ws, size_t ws_size,
                              hipStream_t stream) {
    const float* edges = (const float*)d_in[0];          // [B,Q,N,C] f32
    const int* query_indices  = (const int*)d_in[1];     // [B,T]
    const int* target_indices = (const int*)d_in[2];     // [B,T]
    const int* col_ids        = (const int*)d_in[3];     // [B,G,S]
    const int* edge_tgt       = (const int*)d_in[4];     // [B,G,S]
    float* out = (float*)d_out;                          // [B,Q,B*G]

    edge_cost_fused_kernel<<<BB * (QQ / QPB), 256, 0, stream>>>(
        edges, query_indices, target_indices, col_ids, edge_tgt, out);
}